// Round 1
// baseline (1025.382 us; speedup 1.0000x reference)
//
#include <hip/hip_runtime.h>
#include <hip/hip_bf16.h>
#include <stdint.h>

#define BATCH 8
#define SEQ 2048
#define DMODEL 1024

typedef __attribute__((ext_vector_type(4))) float f32x4;
typedef __attribute__((ext_vector_type(8))) short bf16x8;
typedef __attribute__((ext_vector_type(4))) uint32_t u32x4;
typedef __attribute__((ext_vector_type(2))) uint32_t u32x2;

#define MFMA16(a, b, c) __builtin_amdgcn_mfma_f32_16x16x32_bf16((a), (b), (c), 0, 0, 0)

static __device__ __forceinline__ uint16_t f2bf(float f) {
    uint32_t u = __builtin_bit_cast(uint32_t, f);
    u += 0x7fffu + ((u >> 16) & 1u);   // round-to-nearest-even
    return (uint16_t)(u >> 16);
}
static __device__ __forceinline__ uint32_t pk2(float lo, float hi) {
    return (uint32_t)f2bf(lo) | ((uint32_t)f2bf(hi) << 16);
}

// ---------------------------------------------------------------------------
// Kernel 1: cast + transpose weights. WT[z][n][k] = W_z[k][n], bf16.
// ---------------------------------------------------------------------------
__global__ void wt_cast_kernel(const float* __restrict__ Wk, const float* __restrict__ Wv,
                               const float* __restrict__ Wq, uint16_t* __restrict__ WT) {
    const float* W = blockIdx.z == 0 ? Wk : (blockIdx.z == 1 ? Wv : Wq);
    uint16_t* dst = WT + (size_t)blockIdx.z * DMODEL * DMODEL;
    __shared__ float tile[32][33];
    const int x = blockIdx.x * 32, y = blockIdx.y * 32;
    const int tx = threadIdx.x, ty = threadIdx.y;
#pragma unroll
    for (int j = 0; j < 4; j++)
        tile[ty * 4 + j][tx] = W[(size_t)(y + ty * 4 + j) * DMODEL + x + tx];
    __syncthreads();
#pragma unroll
    for (int j = 0; j < 4; j++)
        dst[(size_t)(x + ty * 4 + j) * DMODEL + y + tx] = f2bf(tile[tx][ty * 4 + j]);
}

// ---------------------------------------------------------------------------
// Kernel 2: projection GEMM.  C[m][n] = sum_k X[m][k] * WT[n][k], bf16 out.
// BM=BN=128, BK=32, 256 thr = 4 waves (2x2), each wave 64x64 via 4x4 16x16x32.
// TSTORE=false: out[m][n] bf16 (Q, K).  TSTORE=true: out[b][n][s] (V -> VT).
// ---------------------------------------------------------------------------
template <bool TSTORE>
__global__ __launch_bounds__(256) void proj_gemm(const float* __restrict__ X,
                                                 const uint16_t* __restrict__ WT,
                                                 uint16_t* __restrict__ out, float scale) {
    constexpr int BM = 128, BK = 32, LDT = 40;  // LDT: padded LDS row stride (80B -> 2-way banks)
    __shared__ __align__(16) uint16_t As[BM * LDT];
    __shared__ __align__(16) uint16_t Bs[BM * LDT];
    const int m0 = blockIdx.x * BM, n0 = blockIdx.y * BM;
    const int t = threadIdx.x, lane = t & 63, wid = t >> 6;
    const int wr = wid >> 1, wc = wid & 1, lr = lane & 15, lg = lane >> 4;
    const int srow = t >> 1, shalf = t & 1;
    const float* xsrc = X + (size_t)(m0 + srow) * DMODEL + shalf * 16;
    const uint16_t* wsrc = WT + (size_t)(n0 + srow) * DMODEL + shalf * 16;
    f32x4 acc[4][4] = {};
    for (int kb = 0; kb < DMODEL; kb += BK) {
        f32x4 x0 = *(const f32x4*)(xsrc + kb);
        f32x4 x1 = *(const f32x4*)(xsrc + kb + 4);
        f32x4 x2 = *(const f32x4*)(xsrc + kb + 8);
        f32x4 x3 = *(const f32x4*)(xsrc + kb + 12);
        u32x4 wv0 = *(const u32x4*)(wsrc + kb);
        u32x4 wv1 = *(const u32x4*)(wsrc + kb + 8);
        u32x4 pa0 = {pk2(x0[0], x0[1]), pk2(x0[2], x0[3]), pk2(x1[0], x1[1]), pk2(x1[2], x1[3])};
        u32x4 pa1 = {pk2(x2[0], x2[1]), pk2(x2[2], x2[3]), pk2(x3[0], x3[1]), pk2(x3[2], x3[3])};
        *(u32x4*)&As[srow * LDT + shalf * 16] = pa0;
        *(u32x4*)&As[srow * LDT + shalf * 16 + 8] = pa1;
        *(u32x4*)&Bs[srow * LDT + shalf * 16] = wv0;
        *(u32x4*)&Bs[srow * LDT + shalf * 16 + 8] = wv1;
        __syncthreads();
        bf16x8 af[4], bfr[4];
#pragma unroll
        for (int i = 0; i < 4; i++) {
            af[i] = *(const bf16x8*)&As[(wr * 64 + i * 16 + lr) * LDT + lg * 8];
            bfr[i] = *(const bf16x8*)&Bs[(wc * 64 + i * 16 + lr) * LDT + lg * 8];
        }
#pragma unroll
        for (int i = 0; i < 4; i++)
#pragma unroll
            for (int j = 0; j < 4; j++)
                acc[i][j] = MFMA16(af[i], bfr[j], acc[i][j]);
        __syncthreads();
    }
    if (!TSTORE) {
#pragma unroll
        for (int i = 0; i < 4; i++)
#pragma unroll
            for (int j = 0; j < 4; j++) {
                const int gm = m0 + wr * 64 + i * 16 + lg * 4;
                const int gn = n0 + wc * 64 + j * 16 + lr;
#pragma unroll
                for (int r = 0; r < 4; r++)
                    out[(size_t)(gm + r) * DMODEL + gn] = f2bf(acc[i][j][r] * scale);
            }
    } else {
        const int bb = m0 / SEQ;          // BM divides SEQ: block never straddles batches
        const int sbase = (m0 % SEQ) + wr * 64;
#pragma unroll
        for (int i = 0; i < 4; i++)
#pragma unroll
            for (int j = 0; j < 4; j++) {
                const int s = sbase + i * 16 + lg * 4;   // 4 consecutive s (C rows)
                const int e = n0 + wc * 64 + j * 16 + lr;
                u32x2 v = {pk2(acc[i][j][0] * scale, acc[i][j][1] * scale),
                           pk2(acc[i][j][2] * scale, acc[i][j][3] * scale)};
                *(u32x2*)&out[((size_t)bb * DMODEL + e) * SEQ + s] = v;
            }
    }
}

// ---------------------------------------------------------------------------
// Kernel 3: softmax stats.  Per (b, 32-row q-block): row max m and sumexp l
// over all 2048 keys.  4 waves, wave w covers keys it*128 + w*32.
// Writes Mrow[b][q] and Lrow[b][q] = 1/l.
// ---------------------------------------------------------------------------
__global__ __launch_bounds__(256) void stats_kernel(const uint16_t* __restrict__ Q,
                                                    const uint16_t* __restrict__ K,
                                                    float* __restrict__ Mrow,
                                                    float* __restrict__ Lrow) {
    __shared__ __align__(16) uint16_t Qs[32 * 1024];  // XOR-swizzled rows
    __shared__ float sm[4][32], sl[4][32];
    const int b = blockIdx.x, q0 = blockIdx.y * 32;
    const int t = threadIdx.x, lane = t & 63, w = t >> 6;
    const int lr = lane & 15, lg = lane >> 4;
    {
        const int row = t >> 3, seg = t & 7;
        const uint16_t* src = Q + (size_t)(b * SEQ + q0 + row) * DMODEL + seg * 128;
        const int sw = (row & 7) << 3;
#pragma unroll
        for (int i = 0; i < 16; i++)
            *(u32x4*)&Qs[row * 1024 + ((seg * 128 + i * 8) ^ sw)] = *(const u32x4*)(src + i * 8);
    }
    __syncthreads();
    float m_loc[8], l_loc[8];
#pragma unroll
    for (int r = 0; r < 8; r++) { m_loc[r] = -3.0e38f; l_loc[r] = 0.0f; }
    const int sw0 = (lr & 7) << 3;  // rows lr and 16+lr share (row&7)
    for (int it = 0; it < 16; it++) {
        const int kb = it * 128 + w * 32;
        f32x4 acc[2][2] = {};
        const uint16_t* kbase = K + (size_t)(b * SEQ + kb + lr) * DMODEL + lg * 8;
#pragma unroll 4
        for (int es = 0; es < 32; es++) {
            bf16x8 a0 = *(const bf16x8*)&Qs[lr * 1024 + ((es * 32 + lg * 8) ^ sw0)];
            bf16x8 a1 = *(const bf16x8*)&Qs[(16 + lr) * 1024 + ((es * 32 + lg * 8) ^ sw0)];
            bf16x8 b0 = *(const bf16x8*)(kbase + es * 32);
            bf16x8 b1 = *(const bf16x8*)(kbase + 16 * DMODEL + es * 32);
            acc[0][0] = MFMA16(a0, b0, acc[0][0]);
            acc[0][1] = MFMA16(a0, b1, acc[0][1]);
            acc[1][0] = MFMA16(a1, b0, acc[1][0]);
            acc[1][1] = MFMA16(a1, b1, acc[1][1]);
        }
#pragma unroll
        for (int qi = 0; qi < 2; qi++)
#pragma unroll
            for (int rg = 0; rg < 4; rg++) {
                const int r = qi * 4 + rg;
                float s0 = acc[qi][0][rg], s1 = acc[qi][1][rg];
                float mx = fmaxf(s0, s1);
                mx = fmaxf(mx, __shfl_xor(mx, 1));
                mx = fmaxf(mx, __shfl_xor(mx, 2));
                mx = fmaxf(mx, __shfl_xor(mx, 4));
                mx = fmaxf(mx, __shfl_xor(mx, 8));
                float mn = fmaxf(m_loc[r], mx);
                float p = __expf(s0 - mn) + __expf(s1 - mn);
                p += __shfl_xor(p, 1);
                p += __shfl_xor(p, 2);
                p += __shfl_xor(p, 4);
                p += __shfl_xor(p, 8);
                l_loc[r] = l_loc[r] * __expf(m_loc[r] - mn) + p;
                m_loc[r] = mn;
            }
    }
    if (lr == 0) {
#pragma unroll
        for (int qi = 0; qi < 2; qi++)
#pragma unroll
            for (int rg = 0; rg < 4; rg++) {
                const int row = qi * 16 + lg * 4 + rg;
                sm[w][row] = m_loc[qi * 4 + rg];
                sl[w][row] = l_loc[qi * 4 + rg];
            }
    }
    __syncthreads();
    if (t < 32) {
        float mm = fmaxf(fmaxf(sm[0][t], sm[1][t]), fmaxf(sm[2][t], sm[3][t]));
        float ll = sl[0][t] * __expf(sm[0][t] - mm) + sl[1][t] * __expf(sm[1][t] - mm) +
                   sl[2][t] * __expf(sm[2][t] - mm) + sl[3][t] * __expf(sm[3][t] - mm);
        Mrow[b * SEQ + q0 + t] = mm;
        Lrow[b * SEQ + q0 + t] = 1.0f / ll;
    }
}

// ---------------------------------------------------------------------------
// Kernel 4: Z = softmax(QK^T) @ V.  Per (b, 32-row q-block), 8 waves.
// Phase A: wave w computes full-E scores for keys it*256+w*32 (+ki*16),
//          p = exp(s - m) -> swizzled LDS P[32][256] bf16.
// Phase B: wave w owns E-slice [w*128, w*128+128): O += P @ VT-slice.
// Epilogue: O *= 1/l, fp32 store.
// ---------------------------------------------------------------------------
__global__ __launch_bounds__(512) void z_kernel(const uint16_t* __restrict__ Q,
                                                const uint16_t* __restrict__ K,
                                                const uint16_t* __restrict__ VT,
                                                const float* __restrict__ Mrow,
                                                const float* __restrict__ Lrow,
                                                float* __restrict__ out) {
    __shared__ __align__(16) uint16_t Qs[32 * 1024];  // 64KB, XOR-swizzled
    __shared__ __align__(16) uint16_t Ps[32 * 256];   // 16KB, XOR-swizzled
    const int b = blockIdx.x, q0 = blockIdx.y * 32;
    const int t = threadIdx.x, lane = t & 63, w = t >> 6;
    const int lr = lane & 15, lg = lane >> 4;
    {
        const int row = t >> 4, seg = t & 15;
        const uint16_t* src = Q + (size_t)(b * SEQ + q0 + row) * DMODEL + seg * 64;
        const int sw = (row & 7) << 3;
#pragma unroll
        for (int i = 0; i < 8; i++)
            *(u32x4*)&Qs[row * 1024 + ((seg * 64 + i * 8) ^ sw)] = *(const u32x4*)(src + i * 8);
    }
    float mr[8], lir[8];
#pragma unroll
    for (int qi = 0; qi < 2; qi++)
#pragma unroll
        for (int rg = 0; rg < 4; rg++) {
            const int row = qi * 16 + lg * 4 + rg;
            mr[qi * 4 + rg] = Mrow[b * SEQ + q0 + row];
            lir[qi * 4 + rg] = Lrow[b * SEQ + q0 + row];
        }
    f32x4 o[2][8] = {};
    const int sw0 = (lr & 7) << 3;
    for (int it = 0; it < 8; it++) {
        __syncthreads();  // covers Q staging (it=0) and P consumption (it>0)
        const int kb = it * 256 + w * 32;
        f32x4 sacc[2][2] = {};
        const uint16_t* kbase = K + (size_t)(b * SEQ + kb + lr) * DMODEL + lg * 8;
#pragma unroll 4
        for (int es = 0; es < 32; es++) {
            bf16x8 a0 = *(const bf16x8*)&Qs[lr * 1024 + ((es * 32 + lg * 8) ^ sw0)];
            bf16x8 a1 = *(const bf16x8*)&Qs[(16 + lr) * 1024 + ((es * 32 + lg * 8) ^ sw0)];
            bf16x8 b0 = *(const bf16x8*)(kbase + es * 32);
            bf16x8 b1 = *(const bf16x8*)(kbase + 16 * DMODEL + es * 32);
            sacc[0][0] = MFMA16(a0, b0, sacc[0][0]);
            sacc[0][1] = MFMA16(a0, b1, sacc[0][1]);
            sacc[1][0] = MFMA16(a1, b0, sacc[1][0]);
            sacc[1][1] = MFMA16(a1, b1, sacc[1][1]);
        }
#pragma unroll
        for (int qi = 0; qi < 2; qi++)
#pragma unroll
            for (int ki = 0; ki < 2; ki++)
#pragma unroll
                for (int rg = 0; rg < 4; rg++) {
                    const int row = qi * 16 + lg * 4 + rg;
                    const int col = w * 32 + ki * 16 + lr;
                    float p = __expf(sacc[qi][ki][rg] - mr[qi * 4 + rg]);
                    Ps[row * 256 + (col ^ ((row & 7) << 3))] = f2bf(p);
                }
        __syncthreads();
        const uint16_t* vbase = VT + ((size_t)b * DMODEL + w * 128 + lr) * SEQ + it * 256 + lg * 8;
#pragma unroll
        for (int kc = 0; kc < 8; kc++) {
            bf16x8 p0 = *(const bf16x8*)&Ps[lr * 256 + ((kc * 32 + lg * 8) ^ sw0)];
            bf16x8 p1 = *(const bf16x8*)&Ps[(16 + lr) * 256 + ((kc * 32 + lg * 8) ^ sw0)];
#pragma unroll
            for (int ni = 0; ni < 8; ni++) {
                bf16x8 bv = *(const bf16x8*)(vbase + (size_t)ni * 16 * SEQ + kc * 32);
                o[0][ni] = MFMA16(p0, bv, o[0][ni]);
                o[1][ni] = MFMA16(p1, bv, o[1][ni]);
            }
        }
    }
#pragma unroll
    for (int qi = 0; qi < 2; qi++)
#pragma unroll
        for (int ni = 0; ni < 8; ni++)
#pragma unroll
            for (int rg = 0; rg < 4; rg++) {
                const int row = qi * 16 + lg * 4 + rg;
                out[(size_t)(b * SEQ + q0 + row) * DMODEL + w * 128 + ni * 16 + lr] =
                    o[qi][ni][rg] * lir[qi * 4 + rg];
            }
}

// ---------------------------------------------------------------------------
// Workspace layout (bytes):
//   Qbf  [16384][1024] bf16 :       0 .. 33,554,432   (Q pre-scaled by 1/32)
//   Kbf  [16384][1024] bf16 :  33,554,432
//   VTb  [8][1024][2048] bf16: 67,108,864
//   WT   [3][1024][1024] bf16: 100,663,296  (order: K, V, Q)
//   Mrow [8][2048] f32      : 106,954,752
//   Lrow [8][2048] f32      : 107,020,288   -> total ~102.1 MiB
// ---------------------------------------------------------------------------
extern "C" void kernel_launch(void* const* d_in, const int* in_sizes, int n_in,
                              void* d_out, int out_size, void* d_ws, size_t ws_size,
                              hipStream_t stream) {
    const float* Xk = (const float*)d_in[0];
    const float* Xv = (const float*)d_in[1];
    const float* Xq = (const float*)d_in[2];
    const float* Wk = (const float*)d_in[3];
    const float* Wv = (const float*)d_in[4];
    const float* Wq = (const float*)d_in[5];
    float* out = (float*)d_out;
    char* ws = (char*)d_ws;
    uint16_t* Qbf = (uint16_t*)(ws);
    uint16_t* Kbf = (uint16_t*)(ws + (size_t)33554432);
    uint16_t* VTb = (uint16_t*)(ws + (size_t)67108864);
    uint16_t* WT = (uint16_t*)(ws + (size_t)100663296);
    float* Mrow = (float*)(ws + (size_t)106954752);
    float* Lrow = (float*)(ws + (size_t)107020288);

    wt_cast_kernel<<<dim3(32, 32, 3), dim3(32, 8), 0, stream>>>(Wk, Wv, Wq, WT);
    // Q gets the 1/sqrt(1024) score scale folded in.
    proj_gemm<false><<<dim3(128, 8), 256, 0, stream>>>(Xq, WT + 2 * 1048576, Qbf, 0.03125f);
    proj_gemm<false><<<dim3(128, 8), 256, 0, stream>>>(Xk, WT, Kbf, 1.0f);
    proj_gemm<true><<<dim3(128, 8), 256, 0, stream>>>(Xv, WT + 1048576, VTb, 1.0f);
    // blockIdx.x = batch -> batch b pinned to XCD b (round-robin %8) for K/VT L2 locality.
    stats_kernel<<<dim3(8, 64), 256, 0, stream>>>(Qbf, Kbf, Mrow, Lrow);
    z_kernel<<<dim3(8, 64), 512, 0, stream>>>(Qbf, Kbf, VTb, Mrow, Lrow, out);
}

// Round 2
// 500.909 us; speedup vs baseline: 2.0470x; 2.0470x over previous
//
#include <hip/hip_runtime.h>
#include <hip/hip_bf16.h>
#include <stdint.h>

#define BATCH 8
#define SEQ 2048
#define DMODEL 1024

typedef __attribute__((ext_vector_type(4))) float f32x4;
typedef __attribute__((ext_vector_type(8))) short bf16x8;
typedef __attribute__((ext_vector_type(4))) uint32_t u32x4;
typedef __attribute__((ext_vector_type(2))) uint32_t u32x2;

#define MFMA16(a, b, c) __builtin_amdgcn_mfma_f32_16x16x32_bf16((a), (b), (c), 0, 0, 0)

static __device__ __forceinline__ uint16_t f2bf(float f) {
    uint32_t u = __builtin_bit_cast(uint32_t, f);
    u += 0x7fffu + ((u >> 16) & 1u);   // round-to-nearest-even
    return (uint16_t)(u >> 16);
}
static __device__ __forceinline__ uint32_t pk2(float lo, float hi) {
    return (uint32_t)f2bf(lo) | ((uint32_t)f2bf(hi) << 16);
}
// async global->LDS, 16B per lane. LDS dest must be linear (wave base + lane*16).
static __device__ __forceinline__ void gload16(const uint16_t* g, uint16_t* l) {
    __builtin_amdgcn_global_load_lds((const __attribute__((address_space(1))) void*)g,
                                     (__attribute__((address_space(3))) void*)l, 16, 0, 0);
}

// ---------------------------------------------------------------------------
// Kernel 1: cast + transpose weights. WT[z][n][k] = W_z[k][n], bf16.
// ---------------------------------------------------------------------------
__global__ void wt_cast_kernel(const float* __restrict__ Wk, const float* __restrict__ Wv,
                               const float* __restrict__ Wq, uint16_t* __restrict__ WT) {
    const float* W = blockIdx.z == 0 ? Wk : (blockIdx.z == 1 ? Wv : Wq);
    uint16_t* dst = WT + (size_t)blockIdx.z * DMODEL * DMODEL;
    __shared__ float tile[32][33];
    const int x = blockIdx.x * 32, y = blockIdx.y * 32;
    const int tx = threadIdx.x, ty = threadIdx.y;
#pragma unroll
    for (int j = 0; j < 4; j++)
        tile[ty * 4 + j][tx] = W[(size_t)(y + ty * 4 + j) * DMODEL + x + tx];
    __syncthreads();
#pragma unroll
    for (int j = 0; j < 4; j++)
        dst[(size_t)(x + ty * 4 + j) * DMODEL + y + tx] = f2bf(tile[tx][ty * 4 + j]);
}

// ---------------------------------------------------------------------------
// Kernel 2: projection GEMM (X f32 * WT^T -> bf16).  Unchanged from round 1.
// ---------------------------------------------------------------------------
template <bool TSTORE>
__global__ __launch_bounds__(256) void proj_gemm(const float* __restrict__ X,
                                                 const uint16_t* __restrict__ WT,
                                                 uint16_t* __restrict__ out, float scale) {
    constexpr int BM = 128, BK = 32, LDT = 40;
    __shared__ __align__(16) uint16_t As[BM * LDT];
    __shared__ __align__(16) uint16_t Bs[BM * LDT];
    const int m0 = blockIdx.x * BM, n0 = blockIdx.y * BM;
    const int t = threadIdx.x, lane = t & 63, wid = t >> 6;
    const int wr = wid >> 1, wc = wid & 1, lr = lane & 15, lg = lane >> 4;
    const int srow = t >> 1, shalf = t & 1;
    const float* xsrc = X + (size_t)(m0 + srow) * DMODEL + shalf * 16;
    const uint16_t* wsrc = WT + (size_t)(n0 + srow) * DMODEL + shalf * 16;
    f32x4 acc[4][4] = {};
    for (int kb = 0; kb < DMODEL; kb += BK) {
        f32x4 x0 = *(const f32x4*)(xsrc + kb);
        f32x4 x1 = *(const f32x4*)(xsrc + kb + 4);
        f32x4 x2 = *(const f32x4*)(xsrc + kb + 8);
        f32x4 x3 = *(const f32x4*)(xsrc + kb + 12);
        u32x4 wv0 = *(const u32x4*)(wsrc + kb);
        u32x4 wv1 = *(const u32x4*)(wsrc + kb + 8);
        u32x4 pa0 = {pk2(x0[0], x0[1]), pk2(x0[2], x0[3]), pk2(x1[0], x1[1]), pk2(x1[2], x1[3])};
        u32x4 pa1 = {pk2(x2[0], x2[1]), pk2(x2[2], x2[3]), pk2(x3[0], x3[1]), pk2(x3[2], x3[3])};
        *(u32x4*)&As[srow * LDT + shalf * 16] = pa0;
        *(u32x4*)&As[srow * LDT + shalf * 16 + 8] = pa1;
        *(u32x4*)&Bs[srow * LDT + shalf * 16] = wv0;
        *(u32x4*)&Bs[srow * LDT + shalf * 16 + 8] = wv1;
        __syncthreads();
        bf16x8 af[4], bfr[4];
#pragma unroll
        for (int i = 0; i < 4; i++) {
            af[i] = *(const bf16x8*)&As[(wr * 64 + i * 16 + lr) * LDT + lg * 8];
            bfr[i] = *(const bf16x8*)&Bs[(wc * 64 + i * 16 + lr) * LDT + lg * 8];
        }
#pragma unroll
        for (int i = 0; i < 4; i++)
#pragma unroll
            for (int j = 0; j < 4; j++)
                acc[i][j] = MFMA16(af[i], bfr[j], acc[i][j]);
        __syncthreads();
    }
    if (!TSTORE) {
#pragma unroll
        for (int i = 0; i < 4; i++)
#pragma unroll
            for (int j = 0; j < 4; j++) {
                const int gm = m0 + wr * 64 + i * 16 + lg * 4;
                const int gn = n0 + wc * 64 + j * 16 + lr;
#pragma unroll
                for (int r = 0; r < 4; r++)
                    out[(size_t)(gm + r) * DMODEL + gn] = f2bf(acc[i][j][r] * scale);
            }
    } else {
        const int bb = m0 / SEQ;
        const int sbase = (m0 % SEQ) + wr * 64;
#pragma unroll
        for (int i = 0; i < 4; i++)
#pragma unroll
            for (int j = 0; j < 4; j++) {
                const int s = sbase + i * 16 + lg * 4;
                const int e = n0 + wc * 64 + j * 16 + lr;
                u32x2 v = {pk2(acc[i][j][0] * scale, acc[i][j][1] * scale),
                           pk2(acc[i][j][2] * scale, acc[i][j][3] * scale)};
                *(u32x2*)&out[((size_t)bb * DMODEL + e) * SEQ + s] = v;
            }
    }
}

// ---------------------------------------------------------------------------
// Kernel 3: batched B^T GEMM, bf16 in, 128x128 tile, BK=64, 4 waves (2x2),
// global_load_lds width-16 staging, double-buffered LDS, XOR-swizzle via
// inverse-swizzled global source + swizzled ds_read (linear LDS dest).
//   C[b][m][n] = sum_k A[b][m][k] * Bt[b][n][k]
// SCALED=false: store bf16 C (scores).  SCALED=true: f32 store * Linv[row] (PV).
// ---------------------------------------------------------------------------
template <bool SCALED>
__global__ __launch_bounds__(256) void bt_gemm(const uint16_t* __restrict__ Ag,
                                               const uint16_t* __restrict__ Bg,
                                               void* __restrict__ Cg,
                                               const float* __restrict__ Linv,
                                               int lda, int ldb, int ldc, int nk,
                                               size_t sA, size_t sB, size_t sC) {
    constexpr int BM = 128, BK = 64;
    __shared__ __align__(16) uint16_t As[2][BM * BK];
    __shared__ __align__(16) uint16_t Bs[2][BM * BK];
    const int bz = blockIdx.z;
    const int m0 = blockIdx.x * BM, n0 = blockIdx.y * BM;
    const uint16_t* Ab = Ag + (size_t)bz * sA + (size_t)m0 * lda;
    const uint16_t* Bb = Bg + (size_t)bz * sB + (size_t)n0 * ldb;
    const int t = threadIdx.x, lane = t & 63, wid = t >> 6;
    const int wr = wid >> 1, wc = wid & 1, lr = lane & 15, lg = lane >> 4;
    // staging: chunk c = t + i*256 covers LDS 16B slot c (linear). The data for
    // LDS (row, slot) comes from global (row, slot ^ (row&7))  [involution].
    int aoff[4], boff[4];
#pragma unroll
    for (int i = 0; i < 4; i++) {
        const int c = t + i * 256, r = c >> 3, sl = c & 7;
        const int gs = sl ^ (r & 7);
        aoff[i] = r * lda + gs * 8;
        boff[i] = r * ldb + gs * 8;
    }
    // fragment rows; row&7 == lr&7 for all of them
    const int sw = lr & 7;
    int ra[4], rb[4];
#pragma unroll
    for (int i = 0; i < 4; i++) { ra[i] = wr * 64 + i * 16 + lr; rb[i] = wc * 64 + i * 16 + lr; }
    f32x4 acc[4][4] = {};
    int buf = 0;
#pragma unroll
    for (int i = 0; i < 4; i++) {
        gload16(Ab + aoff[i], &As[0][(t + i * 256) * 8]);
        gload16(Bb + boff[i], &Bs[0][(t + i * 256) * 8]);
    }
    __syncthreads();
    for (int kb = 0; kb < nk; kb++) {
        if (kb + 1 < nk) {
            const int ko = (kb + 1) * BK;
#pragma unroll
            for (int i = 0; i < 4; i++) {
                gload16(Ab + ko + aoff[i], &As[buf ^ 1][(t + i * 256) * 8]);
                gload16(Bb + ko + boff[i], &Bs[buf ^ 1][(t + i * 256) * 8]);
            }
        }
#pragma unroll
        for (int ks = 0; ks < 2; ks++) {
            bf16x8 af[4], bfv[4];
#pragma unroll
            for (int i = 0; i < 4; i++) {
                af[i]  = *(const bf16x8*)&As[buf][ra[i] * BK + ((ks * 4 + lg) ^ sw) * 8];
                bfv[i] = *(const bf16x8*)&Bs[buf][rb[i] * BK + ((ks * 4 + lg) ^ sw) * 8];
            }
#pragma unroll
            for (int i = 0; i < 4; i++)
#pragma unroll
                for (int j = 0; j < 4; j++)
                    acc[i][j] = MFMA16(af[i], bfv[j], acc[i][j]);
        }
        __syncthreads();   // drains next-tile loads (vmcnt 0) + protects buf reuse
        buf ^= 1;
    }
    if (!SCALED) {
        uint16_t* C = (uint16_t*)Cg + (size_t)bz * sC;
#pragma unroll
        for (int i = 0; i < 4; i++) {
            const int gm = m0 + wr * 64 + i * 16 + lg * 4;
#pragma unroll
            for (int j = 0; j < 4; j++) {
                const int gn = n0 + wc * 64 + j * 16 + lr;
#pragma unroll
                for (int r = 0; r < 4; r++)
                    C[(size_t)(gm + r) * ldc + gn] = f2bf(acc[i][j][r]);
            }
        }
    } else {
        float* C = (float*)Cg + (size_t)bz * sC;
        const float* LB = Linv + bz * SEQ;
#pragma unroll
        for (int i = 0; i < 4; i++) {
            const int gm = m0 + wr * 64 + i * 16 + lg * 4;
            const f32x4 lv = *(const f32x4*)&LB[gm];
#pragma unroll
            for (int j = 0; j < 4; j++) {
                const int gn = n0 + wc * 64 + j * 16 + lr;
#pragma unroll
                for (int r = 0; r < 4; r++)
                    C[(size_t)(gm + r) * ldc + gn] = acc[i][j][r] * lv[r];
            }
        }
    }
}

// ---------------------------------------------------------------------------
// Kernel 4: row softmax, in place.  One block per row (16384 blocks).
// Row (2048 bf16) lives in registers; block max -> p=exp(s-m) -> block sum.
// Writes P bf16 over S and Linv[row] = 1/l.
// ---------------------------------------------------------------------------
__global__ __launch_bounds__(256) void softmax_rows(uint16_t* __restrict__ S,
                                                    float* __restrict__ Linv) {
    const size_t row = blockIdx.x;
    uint16_t* s = S + row * SEQ;
    const int t = threadIdx.x, lane = t & 63, w = t >> 6;
    __shared__ float redm[4], reds[4];
    u32x4 raw = *(const u32x4*)(s + t * 8);
    float v[8];
#pragma unroll
    for (int j = 0; j < 4; j++) {
        v[2 * j]     = __builtin_bit_cast(float, raw[j] << 16);
        v[2 * j + 1] = __builtin_bit_cast(float, raw[j] & 0xffff0000u);
    }
    float m = v[0];
#pragma unroll
    for (int i = 1; i < 8; i++) m = fmaxf(m, v[i]);
#pragma unroll
    for (int d = 1; d < 64; d <<= 1) m = fmaxf(m, __shfl_xor(m, d));
    if (lane == 0) redm[w] = m;
    __syncthreads();
    m = fmaxf(fmaxf(redm[0], redm[1]), fmaxf(redm[2], redm[3]));
    float p[8], sum = 0.0f;
#pragma unroll
    for (int i = 0; i < 8; i++) { p[i] = __expf(v[i] - m); sum += p[i]; }
#pragma unroll
    for (int d = 1; d < 64; d <<= 1) sum += __shfl_xor(sum, d);
    if (lane == 0) reds[w] = sum;
    __syncthreads();
    sum = reds[0] + reds[1] + reds[2] + reds[3];
    u32x4 outp;
#pragma unroll
    for (int j = 0; j < 4; j++) outp[j] = pk2(p[2 * j], p[2 * j + 1]);
    *(u32x4*)(s + t * 8) = outp;
    if (t == 0) Linv[row] = 1.0f / sum;
}

// ---------------------------------------------------------------------------
// Workspace layout (bytes):
//   Qbf [16384][1024] bf16 :          0   (Q pre-scaled by 1/32)
//   Kbf [16384][1024] bf16 :  33,554,432
//   VTb [8][1024][2048] bf16: 67,108,864
//   WT  [3][1024][1024] bf16:100,663,296
//   Linv[16384] f32        : 106,954,752
//   S/P [8][2048][2048] bf16:107,020,288  (P written in place)  end ~166 MiB
// ---------------------------------------------------------------------------
extern "C" void kernel_launch(void* const* d_in, const int* in_sizes, int n_in,
                              void* d_out, int out_size, void* d_ws, size_t ws_size,
                              hipStream_t stream) {
    const float* Xk = (const float*)d_in[0];
    const float* Xv = (const float*)d_in[1];
    const float* Xq = (const float*)d_in[2];
    const float* Wk = (const float*)d_in[3];
    const float* Wv = (const float*)d_in[4];
    const float* Wq = (const float*)d_in[5];
    float* out = (float*)d_out;
    char* ws = (char*)d_ws;
    uint16_t* Qbf = (uint16_t*)(ws);
    uint16_t* Kbf = (uint16_t*)(ws + (size_t)33554432);
    uint16_t* VTb = (uint16_t*)(ws + (size_t)67108864);
    uint16_t* WT  = (uint16_t*)(ws + (size_t)100663296);
    float*    Linv= (float*)(ws + (size_t)106954752);
    uint16_t* Sb  = (uint16_t*)(ws + (size_t)107020288);

    wt_cast_kernel<<<dim3(32, 32, 3), dim3(32, 8), 0, stream>>>(Wk, Wv, Wq, WT);
    // Q gets the 1/sqrt(1024) score scale folded in.
    proj_gemm<false><<<dim3(128, 8), 256, 0, stream>>>(Xq, WT + 2 * 1048576, Qbf, 0.03125f);
    proj_gemm<false><<<dim3(128, 8), 256, 0, stream>>>(Xk, WT, Kbf, 1.0f);
    proj_gemm<true><<<dim3(128, 8), 256, 0, stream>>>(Xv, WT + 1048576, VTb, 1.0f);
    // scores: S[b][q][k] = Qhat[b] . K[b]^T   (bf16 store)
    bt_gemm<false><<<dim3(16, 16, 8), 256, 0, stream>>>(
        Qbf, Kbf, (void*)Sb, nullptr,
        DMODEL, DMODEL, SEQ, DMODEL / 64,
        (size_t)SEQ * DMODEL, (size_t)SEQ * DMODEL, (size_t)SEQ * SEQ);
    // in-place row softmax -> P, Linv
    softmax_rows<<<dim3(BATCH * SEQ), 256, 0, stream>>>(Sb, Linv);
    // Z[b][q][e] = (P[b] . V[b]) * Linv  (f32 store)
    bt_gemm<true><<<dim3(16, 8, 8), 256, 0, stream>>>(
        Sb, VTb, (void*)out, Linv,
        SEQ, SEQ, DMODEL, SEQ / 64,
        (size_t)SEQ * SEQ, (size_t)DMODEL * SEQ, (size_t)SEQ * DMODEL);
}

// Round 3
// 415.498 us; speedup vs baseline: 2.4678x; 1.2056x over previous
//
#include <hip/hip_runtime.h>
#include <hip/hip_bf16.h>
#include <stdint.h>

#define BATCH 8
#define SEQ 2048
#define DMODEL 1024

typedef __attribute__((ext_vector_type(4))) float f32x4;
typedef __attribute__((ext_vector_type(8))) short bf16x8;
typedef __attribute__((ext_vector_type(4))) uint32_t u32x4;
typedef __attribute__((ext_vector_type(2))) uint32_t u32x2;

#define MFMA16(a, b, c) __builtin_amdgcn_mfma_f32_16x16x32_bf16((a), (b), (c), 0, 0, 0)

static __device__ __forceinline__ uint16_t f2bf(float f) {
    uint32_t u = __builtin_bit_cast(uint32_t, f);
    u += 0x7fffu + ((u >> 16) & 1u);   // round-to-nearest-even
    return (uint16_t)(u >> 16);
}
static __device__ __forceinline__ uint32_t pk2(float lo, float hi) {
    return (uint32_t)f2bf(lo) | ((uint32_t)f2bf(hi) << 16);
}
// async global->LDS, 16B per lane. LDS dest is wave-uniform base + lane*16.
static __device__ __forceinline__ void gload16(const uint16_t* g, uint16_t* l) {
    __builtin_amdgcn_global_load_lds((const __attribute__((address_space(1))) void*)g,
                                     (__attribute__((address_space(3))) void*)l, 16, 0, 0);
}

// ---------------------------------------------------------------------------
// Kernel 0: f32 -> bf16 cast, 8 elems/thread (memory-bound).
// ---------------------------------------------------------------------------
__global__ __launch_bounds__(256) void cast_bf16(const float* __restrict__ src,
                                                 uint16_t* __restrict__ dst) {
    const size_t i = ((size_t)blockIdx.x * 256 + threadIdx.x) * 8;
    f32x4 a = *(const f32x4*)(src + i);
    f32x4 b = *(const f32x4*)(src + i + 4);
    u32x4 o = {pk2(a[0], a[1]), pk2(a[2], a[3]), pk2(b[0], b[1]), pk2(b[2], b[3])};
    *(u32x4*)(dst + i) = o;
}

// ---------------------------------------------------------------------------
// Kernel 1: cast + transpose weights. WT[z][n][k] = W_z[k][n], bf16.
// ---------------------------------------------------------------------------
__global__ void wt_cast_kernel(const float* __restrict__ Wk, const float* __restrict__ Wv,
                               const float* __restrict__ Wq, uint16_t* __restrict__ WT) {
    const float* W = blockIdx.z == 0 ? Wk : (blockIdx.z == 1 ? Wv : Wq);
    uint16_t* dst = WT + (size_t)blockIdx.z * DMODEL * DMODEL;
    __shared__ float tile[32][33];
    const int x = blockIdx.x * 32, y = blockIdx.y * 32;
    const int tx = threadIdx.x, ty = threadIdx.y;
#pragma unroll
    for (int j = 0; j < 4; j++)
        tile[ty * 4 + j][tx] = W[(size_t)(y + ty * 4 + j) * DMODEL + x + tx];
    __syncthreads();
#pragma unroll
    for (int j = 0; j < 4; j++)
        dst[(size_t)(x + ty * 4 + j) * DMODEL + y + tx] = f2bf(tile[tx][ty * 4 + j]);
}

// ---------------------------------------------------------------------------
// Kernel 2: pipelined 256x256 B^T GEMM.  C[b][m][n] = sum_k A[b][m][k]*Bt[b][n][k]
// 8 waves (2Mx4N), BK=32, 3-slot LDS rotation, prefetch depth 2,
// counted vmcnt(8) (never drained in main loop), raw s_barrier, setprio MFMA.
// BK=32 => a wave's fragment read set is a contiguous 1KB LDS block per
// ds_read_b128 group (bijection lane->16B chunk): conflict-free, no swizzle,
// linear gload_lds staging.
// MODE 0: bf16 C[m][n] * scale.  MODE 1: bf16 V-transpose store out[b][n][s].
// MODE 2: f32 C[m][n] * Linv[row].
// ---------------------------------------------------------------------------
#define STAGE(tile, s)                                        \
    do {                                                      \
        const size_t ko_ = (size_t)(tile) * 32;               \
        gload16(Ab + ko_ + aoff0, &As[s][t * 8]);             \
        gload16(Ab + ko_ + aoff1, &As[s][t * 8 + 4096]);      \
        gload16(Bb + ko_ + boff0, &Bs[s][t * 8]);             \
        gload16(Bb + ko_ + boff1, &Bs[s][t * 8 + 4096]);      \
    } while (0)

#define KBODY(s, WAITSTR)                                                              \
    do {                                                                               \
        asm volatile("s_waitcnt " WAITSTR ::: "memory");                               \
        __builtin_amdgcn_s_barrier();                                                  \
        bf16x8 bfr[4], afr[8];                                                         \
        _Pragma("unroll") for (int j = 0; j < 4; j++)                                  \
            bfr[j] = *(const bf16x8*)&Bs[s][(wc * 64 + j * 16 + lr) * 32 + lg * 8];    \
        _Pragma("unroll") for (int i = 0; i < 8; i++)                                  \
            afr[i] = *(const bf16x8*)&As[s][(wr * 128 + i * 16 + lr) * 32 + lg * 8];   \
        __builtin_amdgcn_s_setprio(1);                                                 \
        _Pragma("unroll") for (int i = 0; i < 4; i++)                                  \
            _Pragma("unroll") for (int j = 0; j < 4; j++)                              \
                acc[i][j] = MFMA16(afr[i], bfr[j], acc[i][j]);                         \
        __builtin_amdgcn_s_setprio(0);                                                 \
        __builtin_amdgcn_s_setprio(1);                                                 \
        _Pragma("unroll") for (int i = 4; i < 8; i++)                                  \
            _Pragma("unroll") for (int j = 0; j < 4; j++)                              \
                acc[i][j] = MFMA16(afr[i], bfr[j], acc[i][j]);                         \
        __builtin_amdgcn_s_setprio(0);                                                 \
        asm volatile("s_waitcnt lgkmcnt(0)" ::: "memory");                             \
        __builtin_amdgcn_sched_barrier(0);                                             \
        __builtin_amdgcn_s_barrier();                                                  \
    } while (0)

template <int MODE>
__global__ __launch_bounds__(512, 2) void gemm256(const uint16_t* __restrict__ Ag,
                                                  const uint16_t* __restrict__ Bg,
                                                  void* __restrict__ Cg,
                                                  const float* __restrict__ Linv,
                                                  float scale, int lda, int ldb, int ldc,
                                                  int nk, size_t sA, size_t sB, size_t sC) {
    __shared__ __align__(16) uint16_t As[3][256 * 32];
    __shared__ __align__(16) uint16_t Bs[3][256 * 32];
    const int bz = blockIdx.z;
    const int m0 = blockIdx.x * 256, n0 = blockIdx.y * 256;
    const uint16_t* Ab = Ag + (size_t)bz * sA + (size_t)m0 * lda;
    const uint16_t* Bb = Bg + (size_t)bz * sB + (size_t)n0 * ldb;
    const int t = threadIdx.x, lane = t & 63;
    const int wid = t >> 6, wr = wid >> 2, wc = wid & 3;
    const int lr = lane & 15, lg = lane >> 4;
    // linear staging: chunk c in {t, t+512}: row = c>>2, 16B-slot = c&3
    const int srow = t >> 2, sslot = t & 3;
    const size_t aoff0 = (size_t)srow * lda + sslot * 8;
    const size_t aoff1 = aoff0 + (size_t)128 * lda;
    const size_t boff0 = (size_t)srow * ldb + sslot * 8;
    const size_t boff1 = boff0 + (size_t)128 * ldb;

    f32x4 acc[8][4] = {};
    STAGE(0, 0);
    STAGE(1, 1);
    int s = 0, s2 = 2;
    for (int kt = 0; kt < nk - 2; ++kt) {
        STAGE(kt + 2, s2);
        KBODY(s, "vmcnt(8)");
        s = (s == 2) ? 0 : s + 1;
        s2 = (s2 == 2) ? 0 : s2 + 1;
    }
    KBODY(s, "vmcnt(4)");
    s = (s == 2) ? 0 : s + 1;
    KBODY(s, "vmcnt(0)");

    if constexpr (MODE == 0) {
        uint16_t* C = (uint16_t*)Cg + (size_t)bz * sC;
#pragma unroll
        for (int i = 0; i < 8; i++) {
            const int gm = m0 + wr * 128 + i * 16 + lg * 4;
#pragma unroll
            for (int j = 0; j < 4; j++) {
                const int gn = n0 + wc * 64 + j * 16 + lr;
#pragma unroll
                for (int r = 0; r < 4; r++)
                    C[(size_t)(gm + r) * ldc + gn] = f2bf(acc[i][j][r] * scale);
            }
        }
    } else if constexpr (MODE == 1) {
        uint16_t* C = (uint16_t*)Cg;
#pragma unroll
        for (int i = 0; i < 8; i++) {
            const int gm = m0 + wr * 128 + i * 16 + lg * 4;  // global m = b*SEQ + s
            const int bb = gm / SEQ;                         // 256 | SEQ: uniform per block
            const int sx = gm - bb * SEQ;
#pragma unroll
            for (int j = 0; j < 4; j++) {
                const int e = n0 + wc * 64 + j * 16 + lr;
                u32x2 v = {pk2(acc[i][j][0], acc[i][j][1]), pk2(acc[i][j][2], acc[i][j][3])};
                *(u32x2*)&C[((size_t)bb * DMODEL + e) * SEQ + sx] = v;
            }
        }
    } else {
        float* C = (float*)Cg + (size_t)bz * sC;
        const float* LB = Linv + bz * SEQ;
#pragma unroll
        for (int i = 0; i < 8; i++) {
            const int gm = m0 + wr * 128 + i * 16 + lg * 4;
            const f32x4 lv = *(const f32x4*)&LB[gm];
#pragma unroll
            for (int j = 0; j < 4; j++) {
                const int gn = n0 + wc * 64 + j * 16 + lr;
#pragma unroll
                for (int r = 0; r < 4; r++)
                    C[(size_t)(gm + r) * ldc + gn] = acc[i][j][r] * lv[r];
            }
        }
    }
}

// ---------------------------------------------------------------------------
// Kernel 3: row softmax, in place.  One block per row (16384 blocks).
// ---------------------------------------------------------------------------
__global__ __launch_bounds__(256) void softmax_rows(uint16_t* __restrict__ S,
                                                    float* __restrict__ Linv) {
    const size_t row = blockIdx.x;
    uint16_t* s = S + row * SEQ;
    const int t = threadIdx.x, lane = t & 63, w = t >> 6;
    __shared__ float redm[4], reds[4];
    u32x4 raw = *(const u32x4*)(s + t * 8);
    float v[8];
#pragma unroll
    for (int j = 0; j < 4; j++) {
        v[2 * j]     = __builtin_bit_cast(float, raw[j] << 16);
        v[2 * j + 1] = __builtin_bit_cast(float, raw[j] & 0xffff0000u);
    }
    float m = v[0];
#pragma unroll
    for (int i = 1; i < 8; i++) m = fmaxf(m, v[i]);
#pragma unroll
    for (int d = 1; d < 64; d <<= 1) m = fmaxf(m, __shfl_xor(m, d));
    if (lane == 0) redm[w] = m;
    __syncthreads();
    m = fmaxf(fmaxf(redm[0], redm[1]), fmaxf(redm[2], redm[3]));
    float p[8], sum = 0.0f;
#pragma unroll
    for (int i = 0; i < 8; i++) { p[i] = __expf(v[i] - m); sum += p[i]; }
#pragma unroll
    for (int d = 1; d < 64; d <<= 1) sum += __shfl_xor(sum, d);
    if (lane == 0) reds[w] = sum;
    __syncthreads();
    sum = reds[0] + reds[1] + reds[2] + reds[3];
    u32x4 outp;
#pragma unroll
    for (int j = 0; j < 4; j++) outp[j] = pk2(p[2 * j], p[2 * j + 1]);
    *(u32x4*)(s + t * 8) = outp;
    if (t == 0) Linv[row] = 1.0f / sum;
}

// ---------------------------------------------------------------------------
// Workspace layout (bytes):
//   Qbf [16384][1024] bf16 :          0   (Q pre-scaled by 1/32)
//   Kbf [16384][1024] bf16 :  33,554,432
//   VTb [8][1024][2048] bf16: 67,108,864
//   WT  [3][1024][1024] bf16:100,663,296
//   Linv[16384] f32        : 106,954,752
//   S/P [8][2048][2048] bf16:107,020,288  (P in place)
//   Xbf [16384][1024] bf16 :171,966,464   (reused for Xq, Xk, Xv in turn)
// ---------------------------------------------------------------------------
extern "C" void kernel_launch(void* const* d_in, const int* in_sizes, int n_in,
                              void* d_out, int out_size, void* d_ws, size_t ws_size,
                              hipStream_t stream) {
    const float* Xk = (const float*)d_in[0];
    const float* Xv = (const float*)d_in[1];
    const float* Xq = (const float*)d_in[2];
    const float* Wk = (const float*)d_in[3];
    const float* Wv = (const float*)d_in[4];
    const float* Wq = (const float*)d_in[5];
    float* out = (float*)d_out;
    char* ws = (char*)d_ws;
    uint16_t* Qbf = (uint16_t*)(ws);
    uint16_t* Kbf = (uint16_t*)(ws + (size_t)33554432);
    uint16_t* VTb = (uint16_t*)(ws + (size_t)67108864);
    uint16_t* WT  = (uint16_t*)(ws + (size_t)100663296);
    float*    Linv= (float*)(ws + (size_t)106954752);
    uint16_t* Sb  = (uint16_t*)(ws + (size_t)107020288);
    uint16_t* Xbf = (uint16_t*)(ws + (size_t)171966464);

    wt_cast_kernel<<<dim3(32, 32, 3), dim3(32, 8), 0, stream>>>(Wk, Wv, Wq, WT);
    // Q projection (scale 1/sqrt(1024) folded into bf16 store)
    cast_bf16<<<8192, 256, 0, stream>>>(Xq, Xbf);
    gemm256<0><<<dim3(64, 4, 1), 512, 0, stream>>>(
        Xbf, WT + 2 * 1048576, (void*)Qbf, nullptr, 0.03125f,
        DMODEL, DMODEL, DMODEL, DMODEL / 32, 0, 0, 0);
    // K projection
    cast_bf16<<<8192, 256, 0, stream>>>(Xk, Xbf);
    gemm256<0><<<dim3(64, 4, 1), 512, 0, stream>>>(
        Xbf, WT, (void*)Kbf, nullptr, 1.0f,
        DMODEL, DMODEL, DMODEL, DMODEL / 32, 0, 0, 0);
    // V projection with transposed store -> VT[b][e][s]
    cast_bf16<<<8192, 256, 0, stream>>>(Xv, Xbf);
    gemm256<1><<<dim3(64, 4, 1), 512, 0, stream>>>(
        Xbf, WT + 1048576, (void*)VTb, nullptr, 1.0f,
        DMODEL, DMODEL, 0, DMODEL / 32, 0, 0, 0);
    // scores: S[b][q][k] = Qhat[b] . K[b]^T   (bf16 store)
    gemm256<0><<<dim3(8, 8, 8), 512, 0, stream>>>(
        Qbf, Kbf, (void*)Sb, nullptr, 1.0f,
        DMODEL, DMODEL, SEQ, DMODEL / 32,
        (size_t)SEQ * DMODEL, (size_t)SEQ * DMODEL, (size_t)SEQ * SEQ);
    // in-place row softmax -> P, Linv
    softmax_rows<<<dim3(BATCH * SEQ), 256, 0, stream>>>(Sb, Linv);
    // Z[b][q][e] = (P[b] . V[b]) * Linv  (f32 store)
    gemm256<2><<<dim3(8, 4, 8), 512, 0, stream>>>(
        Sb, VTb, (void*)out, Linv, 1.0f,
        SEQ, SEQ, DMODEL, SEQ / 32,
        (size_t)SEQ * SEQ, (size_t)DMODEL * SEQ, (size_t)SEQ * DMODEL);
}